// Round 3
// baseline (288.228 us; speedup 1.0000x reference)
//
#include <hip/hip_runtime.h>

// Sequential2D: out[i] = sum_{j in [max(0,i-2), i]} X[j] @ W[i,j]^T + sum_j b[i,j]
// X (8,32768,128) f32, W (8,8,128,128) f32, b (8,8,128) f32, out (8,32768,128) f32.
//
// R5: kill the barrier vmcnt(0) drain. R0/R3/R4 all plateaued at 2.4-2.8 TB/s
// with every pipe idle because __syncthreads() drains vmcnt(0) at every
// j-boundary -> the X prefetch ring is force-completed and each wave re-exposes
// full memory latency ~3x per wg. This round: raw s_barrier with lgkmcnt-only
// drain (m201 pattern) so ring loads stay in flight across the W-tile publish;
// 8 waves x 16 rows (acc 32 VGPR) so VGPR fits 128 -> 2 wg/CU resident (one
// wg's stage phase hides under the other's MFMA phase); NT stores reverted
// (R4: WRITE_SIZE 132->177 MB regression).

#define NOUT  8
#define NIN   8
#define DD    128
#define BATCH 32768
#define BAND  2

#define BM    128        // batch rows per workgroup (8 waves x 16 rows)
#define SKW   136        // padded LDS stride (shorts): 272B row stride -> 2-way max (free)

typedef __attribute__((ext_vector_type(8))) short  short8;
typedef __attribute__((ext_vector_type(4))) float  floatx4;

__device__ __forceinline__ unsigned short f2bf(float f) {
    unsigned int u = __float_as_uint(f);
    u += 0x7fffu + ((u >> 16) & 1u);
    return (unsigned short)(u >> 16);
}

__device__ __forceinline__ short8 pack8(floatx4 f0, floatx4 f1) {
    short8 p;
    p[0] = (short)f2bf(f0[0]); p[1] = (short)f2bf(f0[1]);
    p[2] = (short)f2bf(f0[2]); p[3] = (short)f2bf(f0[3]);
    p[4] = (short)f2bf(f1[0]); p[5] = (short)f2bf(f1[1]);
    p[6] = (short)f2bf(f1[2]); p[7] = (short)f2bf(f1[3]);
    return p;
}

// s_barrier without the compiler's vmcnt(0)/lgkmcnt(0) drain.
__device__ __forceinline__ void barrier_nodrain() {
    __builtin_amdgcn_sched_barrier(0);
    __builtin_amdgcn_s_barrier();
    __builtin_amdgcn_sched_barrier(0);
}

__global__ __launch_bounds__(512, 4)
void seq2d_kernel(const float* __restrict__ X,
                  const float* __restrict__ W,
                  const float* __restrict__ Bv,
                  float* __restrict__ out) {
    const int i  = blockIdx.y;
    const int m0 = blockIdx.x * BM;

    __shared__ unsigned short sW[DD * SKW];   // one W block, bf16, n-major, padded
    __shared__ float sbias[DD];

    const int tid  = threadIdx.x;
    const int lane = tid & 63;
    const int wave = tid >> 6;          // 0..7, each owns 16 batch rows
    const int l15  = lane & 15;
    const int quad = lane >> 4;

    int jlo = i - BAND; if (jlo < 0) jlo = 0;
    const int ncs = (i - jlo + 1) * 4;  // k-steps of 32 across the band (>= 4)

    // Per-lane A-fragment base: row = m0 + wave*16 + (lane&15), k-offset quad*8.
    const float* xb = X + (size_t)(m0 + wave * 16 + l15) * DD + quad * 8;

    // Depth-4 prefetch ring; slot index is compile-time everywhere (unrolled ks).
    floatx4 px[4][2];

    auto prefetch = [&](int slot, int c) {
        const int j  = jlo + (c >> 2);
        const int k0 = (c & 3) * 32;
        const float* p = xb + (size_t)j * (BATCH * DD) + k0;
        px[slot][0] = *(const floatx4*)(p);
        px[slot][1] = *(const floatx4*)(p + 4);
    };

    prefetch(0, 0);
    prefetch(1, 1);
    prefetch(2, 2);
    prefetch(3, 3);

    if (tid < DD) {
        float s = 0.f;
        for (int j = jlo; j <= i; ++j)
            s += Bv[(i * NIN + j) * DD + tid];
        sbias[tid] = s;
    }

    floatx4 acc[8];
#pragma unroll
    for (int n = 0; n < 8; ++n)
        acc[n] = (floatx4){0.f, 0.f, 0.f, 0.f};

    // W staging: 512 threads cover 128 rows x 128 cols; thread t -> row t>>2,
    // cols (t&3)*32 .. +31 (8 float4 loads, 4 short8 LDS writes, two halves
    // to limit transient register pressure).
    const int wr_r = tid >> 2;          // 0..127
    const int wr_c = (tid & 3) << 5;    // 0,32,64,96

    int c = 0;
    for (int j = jlo; j <= i; ++j) {
        const float* wsrc = W + (size_t)(i * NIN + j) * DD * DD
                              + (size_t)wr_r * DD + wr_c;

        // Barrier 1: previous tile's LDS reads are consumed (each wave's own
        // reads were lgkm-waited before their MFMAs) -> no waitcnt needed.
        // Crucially: X-ring global loads stay in flight.
        barrier_nodrain();

        {
            floatx4 w0 = *(const floatx4*)(wsrc);
            floatx4 w1 = *(const floatx4*)(wsrc + 4);
            floatx4 w2 = *(const floatx4*)(wsrc + 8);
            floatx4 w3 = *(const floatx4*)(wsrc + 12);
            *(short8*)&sW[wr_r * SKW + wr_c]     = pack8(w0, w1);
            *(short8*)&sW[wr_r * SKW + wr_c + 8] = pack8(w2, w3);
        }
        {
            floatx4 w4 = *(const floatx4*)(wsrc + 16);
            floatx4 w5 = *(const floatx4*)(wsrc + 20);
            floatx4 w6 = *(const floatx4*)(wsrc + 24);
            floatx4 w7 = *(const floatx4*)(wsrc + 28);
            *(short8*)&sW[wr_r * SKW + wr_c + 16] = pack8(w4, w5);
            *(short8*)&sW[wr_r * SKW + wr_c + 24] = pack8(w6, w7);
        }

        // Barrier 2: publish W tile — drain LDS writes only, NOT vmcnt.
        asm volatile("s_waitcnt lgkmcnt(0)" ::: "memory");
        barrier_nodrain();

        // 4 k-steps of K=32; consume ring slot ks, reissue it for step c+4.
#pragma unroll
        for (int ks = 0; ks < 4; ++ks) {
            short8 a = pack8(px[ks][0], px[ks][1]);
            if (c + 4 < ncs) prefetch(ks, c + 4);

#pragma unroll
            for (int nf = 0; nf < 8; ++nf) {
                short8 bfrag = *(const short8*)&sW[(nf * 16 + l15) * SKW + ks * 32 + quad * 8];
                acc[nf] = __builtin_amdgcn_mfma_f32_16x16x32_bf16(a, bfrag, acc[nf], 0, 0, 0);
            }
            ++c;
        }
    }

    // epilogue: C/D layout row=(lane>>4)*4+r, col=lane&15 (verified R1). Plain stores.
    float* outi = out + (size_t)i * BATCH * DD;
    const int m_b = m0 + wave * 16 + quad * 4;
#pragma unroll
    for (int nf = 0; nf < 8; ++nf) {
        const int n_g  = nf * 16 + l15;
        const float bs = sbias[n_g];
#pragma unroll
        for (int r = 0; r < 4; ++r)
            outi[(size_t)(m_b + r) * DD + n_g] = acc[nf][r] + bs;
    }
}

extern "C" void kernel_launch(void* const* d_in, const int* in_sizes, int n_in,
                              void* d_out, int out_size, void* d_ws, size_t ws_size,
                              hipStream_t stream) {
    const float* X  = (const float*)d_in[0];
    const float* W  = (const float*)d_in[1];
    const float* Bv = (const float*)d_in[2];
    float* out = (float*)d_out;

    dim3 grid(BATCH / BM, NOUT);
    seq2d_kernel<<<grid, 512, 0, stream>>>(X, W, Bv, out);
}